// Round 1
// baseline (422.442 us; speedup 1.0000x reference)
//
#include <hip/hip_runtime.h>

typedef float f32x4 __attribute__((ext_vector_type(4)));
typedef short s16x8 __attribute__((ext_vector_type(8)));
typedef unsigned short u16;

#define BN 4
#define CC 256
#define NN 4096
#define RR 8
#define CGG 64

static __device__ __forceinline__ u16 f2bf(float x) {
    unsigned int u = __float_as_uint(x);
    u += 0x7FFF + ((u >> 16) & 1);   // round-to-nearest-even
    return (u16)(u >> 16);
}

// ---------------------------------------------------------------------------
// Kernel 0: transpose weights for scalar-load-friendly access.
// wT[src][c][0..7]=qw[r][c], [8..15]=kw[r][c]   (src0: qL,kL ; src1: qU,kU)
// wvT[a][cp][c] = wv_a[c][cp]                   (a0: vU ; a1: vL)
// ---------------------------------------------------------------------------
__global__ __launch_bounds__(256) void k_wtrans(
    const float* __restrict__ qLw, const float* __restrict__ kLw,
    const float* __restrict__ qUw, const float* __restrict__ kUw,
    const float* __restrict__ vUw, const float* __restrict__ vLw,
    float* __restrict__ wT, float* __restrict__ wvT)
{
    int a = blockIdx.x, t = threadIdx.x;
    const float* qw = a ? qUw : qLw;
    const float* kw = a ? kUw : kLw;
#pragma unroll
    for (int r = 0; r < 8; ++r) {
        wT[((size_t)a * 256 + t) * 16 + r]     = qw[r * 256 + t];
        wT[((size_t)a * 256 + t) * 16 + 8 + r] = kw[r * 256 + t];
    }
    const float* wv = a ? vLw : vUw;
    for (int cp = 0; cp < 64; ++cp)
        wvT[((size_t)a * 64 + cp) * 256 + t] = wv[(size_t)t * 64 + cp];
}

// ---------------------------------------------------------------------------
// Kernel 1: Q/K projections.  qt/kt layout: [attend][b][n][8] fp32.
// src0 (fL): -> qt[0] (qL) and kt[1] (kL).  src1 (fU): -> qt[1] (qU), kt[0] (kU).
// ---------------------------------------------------------------------------
__global__ __launch_bounds__(256) void k_qkprep(
    const float* __restrict__ fL, const float* __restrict__ fU,
    const float* __restrict__ wT,
    const float* __restrict__ qLb, const float* __restrict__ kLb,
    const float* __restrict__ qUb, const float* __restrict__ kUb,
    float* __restrict__ qt, float* __restrict__ kt)
{
    int blk = blockIdx.x;
    int nc = blk & 31, b = (blk >> 5) & 3, src = blk >> 7;
    const float* f = src ? fU : fL;
    int qa = src, ka = 1 - src;
    int t = threadIdx.x;
    int nl = t & 127;
    int cs = __builtin_amdgcn_readfirstlane(t >> 7) * 128;
    int n = nc * 128 + nl;
    const float* fp = f + (size_t)b * 256 * NN + n;
    const float* wbase = wT + (size_t)src * 4096;

    float acc[16];
#pragma unroll
    for (int r = 0; r < 16; ++r) acc[r] = 0.f;

    for (int c = cs; c < cs + 128; ++c) {
        float fv = fp[(size_t)c * NN];
        const float* wr = wbase + (size_t)c * 16;   // uniform -> s_load
#pragma unroll
        for (int r = 0; r < 16; ++r) acc[r] += wr[r] * fv;
    }

    __shared__ float red[2][128][17];
    int cc = t >> 7;
#pragma unroll
    for (int r = 0; r < 16; ++r) red[cc][nl][r] = acc[r];
    __syncthreads();

    if (t < 128) {
        const float* bq = src ? qUb : qLb;
        const float* bk = src ? kUb : kLb;
        int nn = nc * 128 + t;
        float vq[8], vk[8];
#pragma unroll
        for (int r = 0; r < 8; ++r) {
            vq[r] = red[0][t][r]     + red[1][t][r]     + bq[r];
            vk[r] = red[0][t][8 + r] + red[1][t][8 + r] + bk[r];
        }
        float* qo = qt + (((size_t)qa * BN + b) * NN + nn) * 8;
        float* ko = kt + (((size_t)ka * BN + b) * NN + nn) * 8;
        *(float4*)(qo)     = make_float4(vq[0], vq[1], vq[2], vq[3]);
        *(float4*)(qo + 4) = make_float4(vq[4], vq[5], vq[6], vq[7]);
        *(float4*)(ko)     = make_float4(vk[0], vk[1], vk[2], vk[3]);
        *(float4*)(ko + 4) = make_float4(vk[4], vk[5], vk[6], vk[7]);
    }
}

// ---------------------------------------------------------------------------
// Kernel 2: Z[a][b][m] = sum_n exp(q[m].k[n])   (no max-sub; |s| <~ 21, safe fp32)
// ---------------------------------------------------------------------------
__global__ __launch_bounds__(256) void k_zsum(
    const float* __restrict__ qt, const float* __restrict__ kt,
    float* __restrict__ Z)
{
    int blk = blockIdx.x;
    int mc = blk & 63, b = (blk >> 6) & 3, a = blk >> 8;
    int t = threadIdx.x, ml = t & 63;
    int nq = __builtin_amdgcn_readfirstlane(t >> 6);
    int m = mc * 64 + ml;

    const float* qp = qt + (((size_t)a * BN + b) * NN + m) * 8;
    float4 q0 = *(const float4*)(qp);
    float4 q1 = *(const float4*)(qp + 4);
    float q[8] = {q0.x, q0.y, q0.z, q0.w, q1.x, q1.y, q1.z, q1.w};

    const float* kp = kt + (((size_t)a * BN + b) * NN + (size_t)nq * 1024) * 8;
    float zs = 0.f;
    for (int i = 0; i < 1024; ++i) {
        const float* kr = kp + (size_t)i * 8;   // uniform -> scalar loads
        float s = 0.f;
#pragma unroll
        for (int r = 0; r < 8; ++r) s += q[r] * kr[r];
        zs += __expf(s);
    }
    __shared__ float red[4][64];
    red[nq][ml] = zs;
    __syncthreads();
    if (t < 64)
        Z[((size_t)a * BN + b) * NN + mc * 64 + t] =
            red[0][t] + red[1][t] + red[2][t] + red[3][t];
}

// ---------------------------------------------------------------------------
// Kernel 3: vp[a][b][c][m] (bf16) = (grouped_conv + bias) / Z[m]
// a0: vU applied to fU ; a1: vL applied to fL
// ---------------------------------------------------------------------------
__global__ __launch_bounds__(256) void k_vprep(
    const float* __restrict__ fL, const float* __restrict__ fU,
    const float* __restrict__ wvT,
    const float* __restrict__ vUb, const float* __restrict__ vLb,
    const float* __restrict__ Z, u16* __restrict__ vp)
{
    int blk = blockIdx.x;
    int cq = blk & 63, b = (blk >> 6) & 3, a = blk >> 8;
    const float* f    = a ? fL : fU;
    const float* bias = a ? vLb : vUb;
    int c0 = cq * 4, g = c0 >> 6;
    int t = threadIdx.x;
    const float* fg = f + ((size_t)b * 256 + g * 64) * NN;
    const float* wq = wvT + (size_t)a * 64 * 256;
    const float* Zp = Z + ((size_t)a * BN + b) * NN;
    float bj[4];
#pragma unroll
    for (int j = 0; j < 4; ++j) bj[j] = bias[c0 + j];

    for (int p = 0; p < 2; ++p) {
        int m8 = t * 16 + p * 8;
        float acc[4][8];
#pragma unroll
        for (int j = 0; j < 4; ++j)
#pragma unroll
            for (int i = 0; i < 8; ++i) acc[j][i] = 0.f;

        for (int cp = 0; cp < 64; ++cp) {
            const float* frow = fg + (size_t)cp * NN + m8;
            float4 fa = *(const float4*)frow;
            float4 fb = *(const float4*)(frow + 4);
            const float* wr = wq + (size_t)cp * 256 + c0;   // uniform
            float fv[8] = {fa.x, fa.y, fa.z, fa.w, fb.x, fb.y, fb.z, fb.w};
#pragma unroll
            for (int j = 0; j < 4; ++j) {
                float wv = wr[j];
#pragma unroll
                for (int i = 0; i < 8; ++i) acc[j][i] += wv * fv[i];
            }
        }
        float4 z0 = *(const float4*)(Zp + m8);
        float4 z1 = *(const float4*)(Zp + m8 + 4);
        float zr[8] = {1.f/z0.x, 1.f/z0.y, 1.f/z0.z, 1.f/z0.w,
                       1.f/z1.x, 1.f/z1.y, 1.f/z1.z, 1.f/z1.w};
#pragma unroll
        for (int j = 0; j < 4; ++j) {
            u16 o8[8];
#pragma unroll
            for (int i = 0; i < 8; ++i) o8[i] = f2bf((acc[j][i] + bj[j]) * zr[i]);
            uint4 pk;
            pk.x = (unsigned)o8[0] | ((unsigned)o8[1] << 16);
            pk.y = (unsigned)o8[2] | ((unsigned)o8[3] << 16);
            pk.z = (unsigned)o8[4] | ((unsigned)o8[5] << 16);
            pk.w = (unsigned)o8[6] | ((unsigned)o8[7] << 16);
            *(uint4*)(vp + ((((size_t)a * BN + b) * 256) + c0 + j) * NN + m8) = pk;
        }
    }
}

// ---------------------------------------------------------------------------
// Kernel 4: out = base + beta * (vp . exp(q^T k))
// 256 blocks = (a, b, 128-wide n tile); 512 threads; 32-m K-steps, dbuf LDS E.
// ---------------------------------------------------------------------------
__global__ __launch_bounds__(512, 2) void k_main(
    const float* __restrict__ fL, const float* __restrict__ fU,
    const float* __restrict__ qt, const float* __restrict__ kt,
    const u16* __restrict__ vp, const float* __restrict__ beta_p,
    float* __restrict__ out)
{
    int blk = blockIdx.x;
    int nt = blk & 31, b = (blk >> 5) & 3, a = blk >> 7;
    int n0 = nt * 128;
    int t = threadIdx.x;
    int w = t >> 6, l = t & 63;

    __shared__ u16 ebuf[2][128][40];   // [buf][n_local][m_local padded]

    // ---- E-gen setup: thread -> (2 m rows, 4 n cols)
    int em = (t & 15) * 2;        // m-local pair base (0..30)
    int en = (t >> 4) * 4;        // n-local base (0..124)
    const float* kb = kt + (((size_t)a * BN + b) * NN + n0) * 8;
    float kvf[4][8];
#pragma unroll
    for (int j = 0; j < 4; ++j) {
        float4 k0 = *(const float4*)(kb + (size_t)(en + j) * 8);
        float4 k1 = *(const float4*)(kb + (size_t)(en + j) * 8 + 4);
        kvf[j][0]=k0.x; kvf[j][1]=k0.y; kvf[j][2]=k0.z; kvf[j][3]=k0.w;
        kvf[j][4]=k1.x; kvf[j][5]=k1.y; kvf[j][6]=k1.z; kvf[j][7]=k1.w;
    }
    const float* qb = qt + (((size_t)a * BN + b) * NN) * 8;

    // ---- MFMA setup: wave -> (c quarter, n half)
    int cq = w & 3, nh = w >> 2;
    const u16* vpb = vp + (((size_t)a * BN + b) * 256 + cq * 64) * (size_t)NN;

    f32x4 acc[4][4];
#pragma unroll
    for (int i = 0; i < 4; ++i)
#pragma unroll
        for (int j = 0; j < 4; ++j) acc[i][j] = (f32x4)0.f;

    auto egen = [&](int m0, int p) {
        const float* q0p = qb + (size_t)(m0 + em) * 8;
        float4 a0 = *(const float4*)(q0p);
        float4 a1 = *(const float4*)(q0p + 4);
        float4 b0 = *(const float4*)(q0p + 8);
        float4 b1 = *(const float4*)(q0p + 12);
        float qr0[8] = {a0.x,a0.y,a0.z,a0.w,a1.x,a1.y,a1.z,a1.w};
        float qr1[8] = {b0.x,b0.y,b0.z,b0.w,b1.x,b1.y,b1.z,b1.w};
#pragma unroll
        for (int j = 0; j < 4; ++j) {
            float s0 = 0.f, s1 = 0.f;
#pragma unroll
            for (int r = 0; r < 8; ++r) { s0 += qr0[r]*kvf[j][r]; s1 += qr1[r]*kvf[j][r]; }
            unsigned int pk = (unsigned int)f2bf(__expf(s0)) |
                              ((unsigned int)f2bf(__expf(s1)) << 16);
            *(unsigned int*)&ebuf[p][en + j][em] = pk;
        }
    };

    auto mstep = [&](int m0, int p) {
        s16x8 bfr[4];
#pragma unroll
        for (int nf = 0; nf < 4; ++nf) {
            int nb = nh * 64 + nf * 16 + (l & 15);
            bfr[nf] = *(const s16x8*)&ebuf[p][nb][(l >> 4) * 8];
        }
#pragma unroll
        for (int cf = 0; cf < 4; ++cf) {
            const u16* ap = vpb + (size_t)(cf * 16 + (l & 15)) * NN + m0 + (l >> 4) * 8;
            s16x8 af = *(const s16x8*)ap;
#pragma unroll
            for (int nf = 0; nf < 4; ++nf)
                acc[cf][nf] = __builtin_amdgcn_mfma_f32_16x16x32_bf16(
                    af, bfr[nf], acc[cf][nf], 0, 0, 0);
        }
    };

    egen(0, 0);
    for (int k = 0; k < 128; ++k) {
        __syncthreads();
        if (k < 127) egen((k + 1) * 32, (k + 1) & 1);
        mstep(k * 32, k & 1);
    }

    // ---- epilogue: out = base + beta*acc
    float beta = beta_p[0];
    const float* base = a ? fU : fL;
    float* op = out + (size_t)a * ((size_t)BN * CC * NN);
#pragma unroll
    for (int cf = 0; cf < 4; ++cf)
#pragma unroll
        for (int nf = 0; nf < 4; ++nf)
#pragma unroll
            for (int r = 0; r < 4; ++r) {
                int c = cq * 64 + cf * 16 + (l >> 4) * 4 + r;
                int n = n0 + nh * 64 + nf * 16 + (l & 15);
                size_t idx = ((size_t)b * CC + c) * NN + n;
                op[idx] = base[idx] + beta * acc[cf][nf][r];
            }
}

// ---------------------------------------------------------------------------
extern "C" void kernel_launch(void* const* d_in, const int* in_sizes, int n_in,
                              void* d_out, int out_size, void* d_ws, size_t ws_size,
                              hipStream_t stream) {
    const float* fL  = (const float*)d_in[0];
    const float* fU  = (const float*)d_in[1];
    const float* qLw = (const float*)d_in[2];
    const float* qLb = (const float*)d_in[3];
    const float* kUw = (const float*)d_in[4];
    const float* kUb = (const float*)d_in[5];
    const float* vUw = (const float*)d_in[6];
    const float* vUb = (const float*)d_in[7];
    const float* qUw = (const float*)d_in[8];
    const float* qUb = (const float*)d_in[9];
    const float* kLw = (const float*)d_in[10];
    const float* kLb = (const float*)d_in[11];
    const float* vLw = (const float*)d_in[12];
    const float* vLb = (const float*)d_in[13];
    const float* beta = (const float*)d_in[14];

    char* ws = (char*)d_ws;
    float* wT  = (float*)(ws);                 //  32 KB
    float* wvT = (float*)(ws + 32768);         // 128 KB
    float* qt  = (float*)(ws + 163840);        //   1 MB
    float* kt  = (float*)(ws + 1212416);       //   1 MB
    float* Z   = (float*)(ws + 2260992);       // 128 KB
    u16*   vp  = (u16*)  (ws + 2392064);       //  16 MB
    float* out = (float*)d_out;

    k_wtrans<<<2, 256, 0, stream>>>(qLw, kLw, qUw, kUw, vUw, vLw, wT, wvT);
    k_qkprep<<<256, 256, 0, stream>>>(fL, fU, wT, qLb, kLb, qUb, kUb, qt, kt);
    k_zsum<<<512, 256, 0, stream>>>(qt, kt, Z);
    k_vprep<<<512, 256, 0, stream>>>(fL, fU, wvT, vUb, vLb, Z, vp);
    k_main<<<256, 512, 0, stream>>>(fL, fU, qt, kt, vp, beta, out);
}